// Round 6
// baseline (161.113 us; speedup 1.0000x reference)
//
#include <hip/hip_runtime.h>

// TensorTrainEmbedding — R1 structure (proven 95.8 us, 97% of fill BW) plus
// nontemporal hints on the zero-reuse streams:
//   - cores gather (537 MB/dispatch, random over 512 MiB -> no reuse): nt loads
//   - out writes (33 MB, write-once): nt stores
// so the reused tables (start 32 MB + end 32 MB + hs 1.5 MB) can stay resident
// in the 256 MiB Infinity Cache across graph replays instead of being thrashed
// by the core stream. Dedup restructurings (R2-R4) all regressed: the
// bin-serial main loses ~35% BW efficiency, exceeding the 197 MB it saves.
//
// Per element b (one wave each):
//   t[d][s][e] = sum_r cores[h1][d][s][r] * end_core[h2][e][r]
//   out[b][d'*16+d*4+e] = sum_s start_core[h0][d'][s] * t[d][s][e]

#define WPB 4           // waves per block (block = 256 threads)
#define T_STRIDE 20     // LDS stride for t: <=2-way bank alias (free, m136)

// native clang vector type: required by __builtin_nontemporal_load/store
typedef float f32x4 __attribute__((ext_vector_type(4)));

__global__ __launch_bounds__(256) void tt_embed_kernel(
    const int* __restrict__ hs,
    const float* __restrict__ start_core,
    const float* __restrict__ end_core,
    const float* __restrict__ cores,
    float* __restrict__ out,
    int B)
{
    __shared__ __align__(16) float lds_t[WPB][16 * T_STRIDE];

    const int tid  = threadIdx.x;
    const int wave = tid >> 6;
    const int lane = tid & 63;

    int b = blockIdx.x * WPB + wave;
    b = __builtin_amdgcn_readfirstlane(b);   // wave-uniform -> scalar path
    const bool active = (b < B);

    float st[16];   // start row for phase 2 (per-lane d' = lane>>4)
    float t[4];

    if (active) {
        // indices are wave-uniform -> s_load (hs is small, keep cached)
        const int h0 = __builtin_amdgcn_readfirstlane(hs[3 * b + 0]);
        const int h1 = __builtin_amdgcn_readfirstlane(hs[3 * b + 1]);
        const int h2 = __builtin_amdgcn_readfirstlane(hs[3 * b + 2]);

        // ---- phase 1: lane = (d = lane>>4, s = lane&15) owns one core row ----
        // core slice: zero-reuse stream -> NONTEMPORAL (don't pollute L2/L3)
        const f32x4* crp = (const f32x4*)(cores + ((size_t)h1 << 10) + lane * 16);
        float c[16];
        *(f32x4*)(c + 0)  = __builtin_nontemporal_load(crp + 0);
        *(f32x4*)(c + 4)  = __builtin_nontemporal_load(crp + 1);
        *(f32x4*)(c + 8)  = __builtin_nontemporal_load(crp + 2);
        *(f32x4*)(c + 12) = __builtin_nontemporal_load(crp + 3);

        // start row (phase 2 operand): reused table, keep cached
        const float* stp = start_core + ((size_t)h0 << 6) + ((lane >> 4) << 4);
        *(f32x4*)(st + 0)  = *(const f32x4*)(stp + 0);
        *(f32x4*)(st + 4)  = *(const f32x4*)(stp + 4);
        *(f32x4*)(st + 8)  = *(const f32x4*)(stp + 8);
        *(f32x4*)(st + 12) = *(const f32x4*)(stp + 12);

        // v0 = end_core[h2]: wave-uniform -> SGPR broadcast; reused table, cached
        const float* v0p = end_core + ((size_t)h2 << 6);
        #pragma unroll
        for (int e = 0; e < 4; ++e) {
            const float* ve = v0p + e * 16;
            float a = c[0] * ve[0];
            #pragma unroll
            for (int r = 1; r < 16; ++r)
                a = fmaf(c[r], ve[r], a);
            t[e] = a;
        }

        // write t to LDS: index (d*4+e)*T_STRIDE + s
        const int d = lane >> 4;
        const int s = lane & 15;
        #pragma unroll
        for (int e = 0; e < 4; ++e)
            lds_t[wave][(d * 4 + e) * T_STRIDE + s] = t[e];
    }

    __syncthreads();

    if (active) {
        // ---- phase 2: lane = output index o = d'*16 + (d*4+e) ----
        const float* tp = &lds_t[wave][(lane & 15) * T_STRIDE];
        float tt[16];
        *(f32x4*)(tt + 0)  = *(const f32x4*)(tp + 0);
        *(f32x4*)(tt + 4)  = *(const f32x4*)(tp + 4);
        *(f32x4*)(tt + 8)  = *(const f32x4*)(tp + 8);
        *(f32x4*)(tt + 12) = *(const f32x4*)(tp + 12);

        float a = st[0] * tt[0];
        #pragma unroll
        for (int k = 1; k < 16; ++k)
            a = fmaf(st[k], tt[k], a);

        // write-once output -> NONTEMPORAL store (256 B contiguous per wave)
        __builtin_nontemporal_store(a, &out[((size_t)b << 6) + lane]);
    }
}

extern "C" void kernel_launch(void* const* d_in, const int* in_sizes, int n_in,
                              void* d_out, int out_size, void* d_ws, size_t ws_size,
                              hipStream_t stream) {
    const int*   hs         = (const int*)d_in[0];
    const float* start_core = (const float*)d_in[1];
    const float* end_core   = (const float*)d_in[2];
    const float* cores      = (const float*)d_in[3];
    float* out = (float*)d_out;

    const int B = in_sizes[0] / 3;                 // hs is (B, 3)
    const int grid = (B + WPB - 1) / WPB;

    hipLaunchKernelGGL(tt_embed_kernel, dim3(grid), dim3(256), 0, stream,
                       hs, start_core, end_core, cores, out, B);
}

// Round 7
// 95.490 us; speedup vs baseline: 1.6872x; 1.6872x over previous
//
#include <hip/hip_runtime.h>

// TensorTrainEmbedding — final: the R1 kernel, verbatim.
// Per element b (one wave each):
//   t[d][s][e] = sum_r cores[h1][d][s][r] * end_core[h2][e][r]
//   out[b][d'*16+d*4+e] = sum_s start_core[h0][d'][s] * t[d][s][e]
//
// 95.8 us = 6.68 TB/s effective over the 638 MB demand-minimal traffic,
// ~97% of the measured fill-kernel ceiling (6.88 TB/s). Session evidence:
//   R2 (bucketed order):      +26 us  — concurrent cross-XCD misses don't merge
//   R3 (inverted-index dedup): +13 us — bin-serial loop is latency-bound
//   R4 (worklist dedup):      +31 us  — same, despite shorter load chain
//   R6 (nontemporal hints):   +65 us  — nt bypasses L2/L3 that WAS absorbing
//                                        part of the core stream
// Conclusion: demand-minimal bytes at BW ceiling -> roofline.

#define WPB 4           // waves per block (block = 256 threads)
#define T_STRIDE 20     // LDS stride for t: <=2-way bank alias (free, m136)

__global__ __launch_bounds__(256) void tt_embed_kernel(
    const int* __restrict__ hs,
    const float* __restrict__ start_core,
    const float* __restrict__ end_core,
    const float* __restrict__ cores,
    float* __restrict__ out,
    int B)
{
    __shared__ __align__(16) float lds_t[WPB][16 * T_STRIDE];

    const int tid  = threadIdx.x;
    const int wave = tid >> 6;
    const int lane = tid & 63;

    int b = blockIdx.x * WPB + wave;
    b = __builtin_amdgcn_readfirstlane(b);   // wave-uniform -> scalar path
    const bool active = (b < B);

    float st[16];   // start row for phase 2 (per-lane d' = lane>>4)
    float t[4];

    if (active) {
        // indices are wave-uniform -> s_load
        const int h0 = __builtin_amdgcn_readfirstlane(hs[3 * b + 0]);
        const int h1 = __builtin_amdgcn_readfirstlane(hs[3 * b + 1]);
        const int h2 = __builtin_amdgcn_readfirstlane(hs[3 * b + 2]);

        // ---- phase 1: lane = (d = lane>>4, s = lane&15) owns one core row ----
        // core row: 16 contiguous floats at flat offset lane*16 within the 4 KiB slice
        const float* crp = cores + ((size_t)h1 << 10) + lane * 16;
        float c[16];
        *(float4*)(c + 0)  = *(const float4*)(crp + 0);
        *(float4*)(c + 4)  = *(const float4*)(crp + 4);
        *(float4*)(c + 8)  = *(const float4*)(crp + 8);
        *(float4*)(c + 12) = *(const float4*)(crp + 12);

        // start row (phase 2 operand): d' = lane>>4, 16 contiguous floats
        const float* stp = start_core + ((size_t)h0 << 6) + ((lane >> 4) << 4);
        *(float4*)(st + 0)  = *(const float4*)(stp + 0);
        *(float4*)(st + 4)  = *(const float4*)(stp + 4);
        *(float4*)(st + 8)  = *(const float4*)(stp + 8);
        *(float4*)(st + 12) = *(const float4*)(stp + 12);

        // v0 = end_core[h2]: 64 floats, wave-uniform -> SGPR broadcast
        const float* v0p = end_core + ((size_t)h2 << 6);
        #pragma unroll
        for (int e = 0; e < 4; ++e) {
            const float* ve = v0p + e * 16;
            float a = c[0] * ve[0];
            #pragma unroll
            for (int r = 1; r < 16; ++r)
                a = fmaf(c[r], ve[r], a);
            t[e] = a;
        }

        // write t to LDS: index (d*4+e)*T_STRIDE + s
        const int d = lane >> 4;
        const int s = lane & 15;
        #pragma unroll
        for (int e = 0; e < 4; ++e)
            lds_t[wave][(d * 4 + e) * T_STRIDE + s] = t[e];
    }

    __syncthreads();

    if (active) {
        // ---- phase 2: lane = output index o = d'*16 + (d*4+e); de = lane&15 ----
        const float* tp = &lds_t[wave][(lane & 15) * T_STRIDE];
        float tt[16];
        *(float4*)(tt + 0)  = *(const float4*)(tp + 0);
        *(float4*)(tt + 4)  = *(const float4*)(tp + 4);
        *(float4*)(tt + 8)  = *(const float4*)(tp + 8);
        *(float4*)(tt + 12) = *(const float4*)(tp + 12);

        float a = st[0] * tt[0];
        #pragma unroll
        for (int k = 1; k < 16; ++k)
            a = fmaf(st[k], tt[k], a);

        out[((size_t)b << 6) + lane] = a;   // wave writes 256 B contiguous
    }
}

extern "C" void kernel_launch(void* const* d_in, const int* in_sizes, int n_in,
                              void* d_out, int out_size, void* d_ws, size_t ws_size,
                              hipStream_t stream) {
    const int*   hs         = (const int*)d_in[0];
    const float* start_core = (const float*)d_in[1];
    const float* end_core   = (const float*)d_in[2];
    const float* cores      = (const float*)d_in[3];
    float* out = (float*)d_out;

    const int B = in_sizes[0] / 3;                 // hs is (B, 3)
    const int grid = (B + WPB - 1) / WPB;

    hipLaunchKernelGGL(tt_embed_kernel, dim3(grid), dim3(256), 0, stream,
                       hs, start_core, end_core, cores, out, B);
}